// Round 5
// baseline (1726.336 us; speedup 1.0000x reference)
//
#include <hip/hip_runtime.h>
#include <hip/hip_bf16.h>
#include <hip/hip_cooperative_groups.h>

namespace cg = cooperative_groups;

#define NN 10000
#define EE 160000
#define DD 512
#define GG 64
#define OUTC 128
#define NBLK 628

typedef __attribute__((ext_vector_type(8))) short bf16x8;
typedef __attribute__((ext_vector_type(4))) float f32x4;

static __device__ __forceinline__ unsigned short f2bf(float f) {
  unsigned u = __builtin_bit_cast(unsigned, f);
  unsigned rounding = 0x7fffu + ((u >> 16) & 1u);
  u += rounding;
  return (unsigned short)(u >> 16);
}

static __device__ __forceinline__ void gload_lds16(const void* g, void* l) {
  __builtin_amdgcn_global_load_lds(
      (const __attribute__((address_space(1))) unsigned*)g,
      (__attribute__((address_space(3))) unsigned*)l, 16, 0, 0);
}

// ---------------- CSR build ----------------
__global__ void hist_dst(const int* __restrict__ dst, int* __restrict__ cnt) {
  int e = blockIdx.x * 256 + threadIdx.x;
  if (e < EE) atomicAdd(&cnt[dst[e]], 1);
}

__global__ void scan_offsets(const int* __restrict__ cnt, int* __restrict__ offs) {
  __shared__ int wpre[17];
  __shared__ int carry;
  int t = threadIdx.x;            // 1024 threads = 16 waves
  int lane = t & 63, wv = t >> 6;
  if (t == 0) carry = 0;
  __syncthreads();
  for (int base = 0; base < NN; base += 1024) {
    int i = base + t;
    int v = (i < NN) ? cnt[i] : 0;
    int s = v;
#pragma unroll
    for (int d = 1; d < 64; d <<= 1) {
      int o = __shfl_up(s, d, 64);
      if (lane >= d) s += o;
    }
    if (lane == 63) wpre[wv] = s;
    __syncthreads();
    if (t == 0) {
      int r = 0;
      for (int w = 0; w < 16; ++w) { int x = wpre[w]; wpre[w] = r; r += x; }
      wpre[16] = r;
    }
    __syncthreads();
    int incl = s + wpre[wv] + carry;
    if (i < NN) offs[i] = incl - v;   // exclusive prefix
    __syncthreads();
    if (t == 0) carry += wpre[16];
    __syncthreads();
  }
  if (t == 0) offs[NN] = carry;       // == EE
}

__global__ void fill_edges(const int* __restrict__ src, const int* __restrict__ dst,
                           const int* __restrict__ offs, int* __restrict__ fptr,
                           int* __restrict__ ssrc) {
  int e = blockIdx.x * 256 + threadIdx.x;
  if (e < EE) {
    int d = dst[e];
    int p = atomicAdd(&fptr[d], 1);
    ssrc[offs[d] + p] = src[e];
  }
}

// ---------------- weight transpose + bf16 convert ----------------
// W [512 k][512 n] f32 row-major -> WT merged [layer][512 n][1024 k] bf16
// Wr at k 0..511; Ws'+I at k 512..1023 (residual folded: x + x@Ws = x@(Ws+I))
struct WPtrs { const float* p[10]; };
struct BiasP { const float* p[5]; };

__global__ void transpose_w_all(WPtrs wp, unsigned short* __restrict__ WT) {
  __shared__ float tile[32][33];
  int z = blockIdx.z;                 // 0..9: layer z>>1, (z&1)=Ws
  const float* W = wp.p[z];
  unsigned short* dst = WT + (size_t)(z >> 1) * DD * 1024 + (size_t)(z & 1) * DD;
  int bx = blockIdx.x * 32, by = blockIdx.y * 32;
  int tx = threadIdx.x, ty = threadIdx.y;
  for (int i = ty; i < 32; i += 8)
    tile[i][tx] = W[(size_t)(by + i) * DD + bx + tx];
  __syncthreads();
  int addI = z & 1;
  for (int i = ty; i < 32; i += 8) {
    float v = tile[tx][i];
    if (addI && (by + tx) == (bx + i)) v += 1.0f;   // fold residual
    dst[(size_t)(bx + i) * 1024 + by + tx] = f2bf(v);
  }
}

// ---------------- fallback kernels (non-cooperative path) ----------------
__global__ void convert_x(const float* __restrict__ x, unsigned short* __restrict__ m0) {
  int i = blockIdx.x * 256 + threadIdx.x;   // pair index
  if (i < NN * DD / 2) {
    float2 v = ((const float2*)x)[i];
    unsigned u = (unsigned)f2bf(v.x) | ((unsigned)f2bf(v.y) << 16);
    int e = i << 1;
    int row = e >> 9, col = e & 511;
    ((unsigned*)m0)[row * 512 + 256 + (col >> 1)] = u;
  }
}

static __device__ __forceinline__ void acc8(float* a, uint4 v) {
  unsigned w0 = v.x, w1 = v.y, w2 = v.z, w3 = v.w;
  a[0] += __builtin_bit_cast(float, w0 << 16);
  a[1] += __builtin_bit_cast(float, w0 & 0xffff0000u);
  a[2] += __builtin_bit_cast(float, w1 << 16);
  a[3] += __builtin_bit_cast(float, w1 & 0xffff0000u);
  a[4] += __builtin_bit_cast(float, w2 << 16);
  a[5] += __builtin_bit_cast(float, w2 & 0xffff0000u);
  a[6] += __builtin_bit_cast(float, w3 << 16);
  a[7] += __builtin_bit_cast(float, w3 & 0xffff0000u);
}

static __device__ __forceinline__ void seg_node(unsigned short* merged,
                                                const int* offs, const int* ssrc,
                                                int node, int lane) {
  int beg = offs[node], end = offs[node + 1];
  const uint4* xb = (const uint4*)merged;   // row = 128 uint4; right half at +64
  float a[8] = {0.f, 0.f, 0.f, 0.f, 0.f, 0.f, 0.f, 0.f};
  int e = beg;
  for (; e + 8 <= end; e += 8) {
    uint4 v0 = xb[(size_t)ssrc[e] * 128 + 64 + lane];
    uint4 v1 = xb[(size_t)ssrc[e + 1] * 128 + 64 + lane];
    uint4 v2 = xb[(size_t)ssrc[e + 2] * 128 + 64 + lane];
    uint4 v3 = xb[(size_t)ssrc[e + 3] * 128 + 64 + lane];
    uint4 v4 = xb[(size_t)ssrc[e + 4] * 128 + 64 + lane];
    uint4 v5 = xb[(size_t)ssrc[e + 5] * 128 + 64 + lane];
    uint4 v6 = xb[(size_t)ssrc[e + 6] * 128 + 64 + lane];
    uint4 v7 = xb[(size_t)ssrc[e + 7] * 128 + 64 + lane];
    acc8(a, v0); acc8(a, v1); acc8(a, v2); acc8(a, v3);
    acc8(a, v4); acc8(a, v5); acc8(a, v6); acc8(a, v7);
  }
  for (; e + 4 <= end; e += 4) {
    uint4 v0 = xb[(size_t)ssrc[e] * 128 + 64 + lane];
    uint4 v1 = xb[(size_t)ssrc[e + 1] * 128 + 64 + lane];
    uint4 v2 = xb[(size_t)ssrc[e + 2] * 128 + 64 + lane];
    uint4 v3 = xb[(size_t)ssrc[e + 3] * 128 + 64 + lane];
    acc8(a, v0); acc8(a, v1); acc8(a, v2); acc8(a, v3);
  }
  for (; e < end; ++e) {
    uint4 v = xb[(size_t)ssrc[e] * 128 + 64 + lane];
    acc8(a, v);
  }
  uint4 o;
  o.x = (unsigned)f2bf(a[0]) | ((unsigned)f2bf(a[1]) << 16);
  o.y = (unsigned)f2bf(a[2]) | ((unsigned)f2bf(a[3]) << 16);
  o.z = (unsigned)f2bf(a[4]) | ((unsigned)f2bf(a[5]) << 16);
  o.w = (unsigned)f2bf(a[6]) | ((unsigned)f2bf(a[7]) << 16);
  ((uint4*)merged)[(size_t)node * 128 + lane] = o;
}

__global__ __launch_bounds__(256) void seg_sum(unsigned short* __restrict__ merged,
                                               const int* __restrict__ offs,
                                               const int* __restrict__ ssrc) {
  int node = (blockIdx.x << 2) + (threadIdx.x >> 6);
  if (node >= NN) return;
  seg_node(merged, offs, ssrc, node, threadIdx.x & 63);
}

// fallback full-K gemm (no residual read; Ws has I folded)
__global__ __launch_bounds__(256) void gemm_full(
    const unsigned short* __restrict__ Am, const unsigned short* __restrict__ Bw,
    const float* __restrict__ bias, unsigned short* __restrict__ xout, int do_relu) {
  __shared__ unsigned short Al[2][64 * 64];
  __shared__ unsigned short Bl[2][128 * 64];
  int tid = threadIdx.x;
  int lane = tid & 63, wave = tid >> 6;
  int wr = wave >> 1, wc = wave & 1;
  int orig = blockIdx.x;
  int xcd = orig & 7, cidx = orig >> 3;
  int wgid = (xcd < 4) ? xcd * 79 + cidx : 316 + (xcd - 4) * 78 + cidx;
  int brow = (wgid >> 2) * 64;
  int bcol = (wgid & 3) * 128;
  int lrow = lane & 15, lq = lane >> 4;

  f32x4 acc[2][4];
#pragma unroll
  for (int m = 0; m < 2; ++m)
#pragma unroll
    for (int n = 0; n < 4; ++n) acc[m][n] = (f32x4){0.f, 0.f, 0.f, 0.f};

  auto STAGE = [&](int buf, int t) {
    int k0 = t * 64;
#pragma unroll
    for (int i = 0; i < 2; ++i) {
      int idx = i * 256 + tid;
      int row = idx >> 3, c = idx & 7;
      int csw = (c ^ (row & 7)) * 8;
      int gr = brow + row;
      if (gr >= NN) gr = NN - 1;
      gload_lds16(Am + (size_t)gr * 1024 + k0 + csw, &Al[buf][idx * 8]);
    }
#pragma unroll
    for (int i = 0; i < 4; ++i) {
      int idx = i * 256 + tid;
      int row = idx >> 3, c = idx & 7;
      int csw = (c ^ (row & 7)) * 8;
      gload_lds16(Bw + (size_t)(bcol + row) * 1024 + k0 + csw, &Bl[buf][idx * 8]);
    }
  };

  STAGE(0, 0);
  __syncthreads();
  int cur = 0;
#pragma unroll 1
  for (int t = 0; t < 16; ++t) {
    if (t < 15) STAGE(cur ^ 1, t + 1);
#pragma unroll
    for (int kk = 0; kk < 2; ++kk) {
      bf16x8 a[2], b[4];
      int lc = kk * 4 + lq;
#pragma unroll
      for (int m = 0; m < 2; ++m) {
        int row = wr * 32 + m * 16 + lrow;
        a[m] = *(const bf16x8*)&Al[cur][row * 64 + ((lc ^ (lrow & 7)) * 8)];
      }
#pragma unroll
      for (int n = 0; n < 4; ++n) {
        int row = wc * 64 + n * 16 + lrow;
        b[n] = *(const bf16x8*)&Bl[cur][row * 64 + ((lc ^ (lrow & 7)) * 8)];
      }
#pragma unroll
      for (int m = 0; m < 2; ++m)
#pragma unroll
        for (int n = 0; n < 4; ++n)
          acc[m][n] = __builtin_amdgcn_mfma_f32_16x16x32_bf16(a[m], b[n], acc[m][n], 0, 0, 0);
    }
    __syncthreads();
    cur ^= 1;
  }

  int crow = lq * 4, ccol = lrow;
#pragma unroll
  for (int m = 0; m < 2; ++m)
#pragma unroll
    for (int n = 0; n < 4; ++n) {
      int col = bcol + wc * 64 + n * 16 + ccol;
      float bv = bias[col];
#pragma unroll
      for (int i = 0; i < 4; ++i) {
        int row = brow + wr * 32 + m * 16 + crow + i;
        if (row < NN) {
          float v = acc[m][n][i] + bv;
          if (do_relu) v = fmaxf(v, 0.f);
          xout[(size_t)row * 1024 + 512 + col] = f2bf(v);
        }
      }
    }
}

// ---------------- cooperative persistent fused kernel ----------------
// 628 blocks x 256 thr, 48KB LDS -> 3 blocks/CU co-resident.
// Per layer: segsum (grid-stride) ; xWs-half GEMM (overlaps stragglers) ;
// grid.sync ; aggWr-half GEMM ; epilogue ; grid.sync.
__global__ __launch_bounds__(256, 3) void fused_layers(
    const float* __restrict__ x_in,
    unsigned short* __restrict__ m0,
    unsigned short* __restrict__ m1,
    const unsigned short* __restrict__ wt,
    const int* __restrict__ offs,
    const int* __restrict__ ssrc,
    BiasP bp) {
  cg::grid_group grid = cg::this_grid();
  __shared__ unsigned short Al[2][64 * 64];
  __shared__ unsigned short Bl[2][128 * 64];
  int tid = threadIdx.x;
  int lane = tid & 63, wave = tid >> 6;
  int wr = wave >> 1, wc = wave & 1;
  int lrow = lane & 15, lq = lane >> 4;

  // tile via bijective XCD swizzle (628 = 8*78+4)
  int orig = blockIdx.x;
  int xcd = orig & 7, cidx = orig >> 3;
  int wgid = (xcd < 4) ? xcd * 79 + cidx : 316 + (xcd - 4) * 78 + cidx;
  int brow = (wgid >> 2) * 64;
  int bcol = (wgid & 3) * 128;

  // phase 0: x -> bf16 right half of m0
  for (int i = blockIdx.x * 256 + tid; i < NN * DD / 2; i += NBLK * 256) {
    float2 v = ((const float2*)x_in)[i];
    unsigned u = (unsigned)f2bf(v.x) | ((unsigned)f2bf(v.y) << 16);
    int e = i << 1;
    int row = e >> 9, col = e & 511;
    ((unsigned*)m0)[row * 512 + 256 + (col >> 1)] = u;
  }
  __threadfence();
  grid.sync();

  f32x4 acc[2][4];

  auto stage = [&](const unsigned short* Acur, const unsigned short* Bw,
                   int buf, int kk0) {
#pragma unroll
    for (int i = 0; i < 2; ++i) {
      int idx = i * 256 + tid;
      int row = idx >> 3, c = idx & 7;
      int csw = (c ^ (row & 7)) * 8;
      int gr = brow + row;
      if (gr >= NN) gr = NN - 1;
      gload_lds16(Acur + (size_t)gr * 1024 + kk0 + csw, &Al[buf][idx * 8]);
    }
#pragma unroll
    for (int i = 0; i < 4; ++i) {
      int idx = i * 256 + tid;
      int row = idx >> 3, c = idx & 7;
      int csw = (c ^ (row & 7)) * 8;
      gload_lds16(Bw + (size_t)(bcol + row) * 1024 + kk0 + csw, &Bl[buf][idx * 8]);
    }
  };

  auto gemm_half = [&](const unsigned short* Acur, const unsigned short* Bw,
                       int kbase) {
    stage(Acur, Bw, 0, kbase);
    __syncthreads();
    int cur = 0;
#pragma unroll 1
    for (int t = 0; t < 8; ++t) {
      if (t < 7) stage(Acur, Bw, cur ^ 1, kbase + (t + 1) * 64);
#pragma unroll
      for (int kk = 0; kk < 2; ++kk) {
        bf16x8 a[2], b[4];
        int lc = kk * 4 + lq;
#pragma unroll
        for (int m = 0; m < 2; ++m) {
          int row = wr * 32 + m * 16 + lrow;
          a[m] = *(const bf16x8*)&Al[cur][row * 64 + ((lc ^ (lrow & 7)) * 8)];
        }
#pragma unroll
        for (int n = 0; n < 4; ++n) {
          int row = wc * 64 + n * 16 + lrow;
          b[n] = *(const bf16x8*)&Bl[cur][row * 64 + ((lc ^ (lrow & 7)) * 8)];
        }
#pragma unroll
        for (int m = 0; m < 2; ++m)
#pragma unroll
          for (int n = 0; n < 4; ++n)
            acc[m][n] = __builtin_amdgcn_mfma_f32_16x16x32_bf16(a[m], b[n], acc[m][n], 0, 0, 0);
      }
      __syncthreads();
      cur ^= 1;
    }
  };

#pragma unroll
  for (int l = 0; l < 5; ++l) {
    unsigned short* curb = (l & 1) ? m1 : m0;
    unsigned short* nxtb = (l & 1) ? m0 : m1;
    const unsigned short* Bw = wt + (size_t)l * DD * 1024;
    const float* bias = bp.p[l];
    int do_relu = (l < 4);

    // phase A: seg_sum for my share (writes curb left half)
    for (int grp = blockIdx.x; grp < (NN + 3) / 4; grp += NBLK) {
      int node = grp * 4 + wave;
      if (node < NN) seg_node(curb, offs, ssrc, node, lane);
    }

    // phase B: x@Ws' half (k 512..1023) — no dependency on phase A
#pragma unroll
    for (int m = 0; m < 2; ++m)
#pragma unroll
      for (int n = 0; n < 4; ++n) acc[m][n] = (f32x4){0.f, 0.f, 0.f, 0.f};
    gemm_half(curb, Bw, 512);

    __threadfence();
    grid.sync();          // all agg (left halves) now visible

    // phase C: agg@Wr half (k 0..511)
    gemm_half(curb, Bw, 0);

    // epilogue: bias (+relu), residual already folded into Ws'
    int crow = lq * 4, ccol = lrow;
#pragma unroll
    for (int m = 0; m < 2; ++m)
#pragma unroll
      for (int n = 0; n < 4; ++n) {
        int col = bcol + wc * 64 + n * 16 + ccol;
        float bv = bias[col];
#pragma unroll
        for (int i = 0; i < 4; ++i) {
          int row = brow + wr * 32 + m * 16 + crow + i;
          if (row < NN) {
            float v = acc[m][n][i] + bv;
            if (do_relu) v = fmaxf(v, 0.f);
            nxtb[(size_t)row * 1024 + 512 + col] = f2bf(v);
          }
        }
      }
    __threadfence();
    grid.sync();          // x_{l+1} visible for next seg_sum
  }
}

// ---------------- pooling ----------------
__global__ void graph_bounds(const int* __restrict__ batch, int* __restrict__ gstart) {
  int i = blockIdx.x * 256 + threadIdx.x;
  if (i >= NN) return;
  int cur = batch[i];
  int prev = (i == 0) ? -1 : batch[i - 1];
  for (int g = prev + 1; g <= cur; ++g) gstart[g] = i;
  if (i == NN - 1)
    for (int g = cur + 1; g <= GG; ++g) gstart[g] = NN;
}

__global__ __launch_bounds__(256) void pool_partial(const unsigned short* __restrict__ mfin,
                                                    const int* __restrict__ gstart,
                                                    float* __restrict__ pooled) {
  int g = blockIdx.x, part = blockIdx.y;    // 8 parts per graph
  int t = threadIdx.x;
  int beg = gstart[g], end = gstart[g + 1];
  int n = end - beg;
  int per = (n + 7) >> 3;
  int b = beg + part * per;
  int e = b + per; if (e > end) e = end;
  if (b >= e) return;
  const unsigned* mw = (const unsigned*)mfin;
  float a0 = 0.f, a1 = 0.f;
  for (int r = b; r < e; ++r) {
    unsigned v = mw[(size_t)r * 512 + 256 + t];
    a0 += __builtin_bit_cast(float, v << 16);
    a1 += __builtin_bit_cast(float, v & 0xffff0000u);
  }
  atomicAdd(&pooled[g * DD + 2 * t], a0);
  atomicAdd(&pooled[g * DD + 2 * t + 1], a1);
}

__global__ __launch_bounds__(128) void final_linear(const float* __restrict__ pooled,
                                                    const int* __restrict__ gstart,
                                                    const float* __restrict__ Wlin,
                                                    const float* __restrict__ blin,
                                                    float* __restrict__ out) {
  __shared__ float p[128];
  int g = blockIdx.x, kq = blockIdx.y;
  int o = threadIdx.x;
  int cnt = gstart[g + 1] - gstart[g];
  float inv = 1.0f / fmaxf((float)cnt, 1.0f);
  p[o] = pooled[g * DD + kq * 128 + o] * inv;
  __syncthreads();
  float s = (kq == 0) ? blin[o] : 0.f;
#pragma unroll 8
  for (int k = 0; k < 128; ++k)
    s += p[k] * Wlin[(size_t)(kq * 128 + k) * OUTC + o];
  atomicAdd(&out[g * OUTC + o], s);
}

// ---------------- host ----------------
extern "C" void kernel_launch(void* const* d_in, const int* in_sizes, int n_in,
                              void* d_out, int out_size, void* d_ws, size_t ws_size,
                              hipStream_t stream) {
  const float* x_in = (const float*)d_in[0];
  const int* ei = (const int*)d_in[1];
  const int* src = ei;
  const int* dst = ei + EE;
  const int* batch = (const int*)d_in[2];
  WPtrs wp;
  BiasP bp;
  for (int l = 0; l < 5; ++l) {
    wp.p[2 * l] = (const float*)d_in[3 + 3 * l];      // Wr
    wp.p[2 * l + 1] = (const float*)d_in[4 + 3 * l];  // Ws
    bp.p[l] = (const float*)d_in[5 + 3 * l];
  }
  const float* Wlin = (const float*)d_in[18];
  const float* blin = (const float*)d_in[19];
  float* out = (float*)d_out;

  char* ws = (char*)d_ws;
  size_t off = 0;
  auto alloc = [&](size_t bytes) { size_t o = off; off += (bytes + 511) & ~(size_t)511; return o; };
  unsigned short* m0 = (unsigned short*)(ws + alloc((size_t)NN * 1024 * 2));
  unsigned short* m1 = (unsigned short*)(ws + alloc((size_t)NN * 1024 * 2));
  unsigned short* wt = (unsigned short*)(ws + alloc((size_t)5 * DD * 1024 * 2));
  int* deg = (int*)(ws + alloc((size_t)NN * 4));
  int* offs = (int*)(ws + alloc((size_t)(NN + 1) * 4));
  int* fptr = (int*)(ws + alloc((size_t)NN * 4));
  int* ssrc = (int*)(ws + alloc((size_t)EE * 4));
  int* gstart = (int*)(ws + alloc((size_t)(GG + 1) * 4));
  float* pooled = (float*)(ws + alloc((size_t)GG * DD * 4));

  hipMemsetAsync(deg, 0, (size_t)NN * 4, stream);
  hipMemsetAsync(fptr, 0, (size_t)NN * 4, stream);
  hipMemsetAsync(pooled, 0, (size_t)GG * DD * 4, stream);
  hipMemsetAsync(out, 0, (size_t)GG * OUTC * 4, stream);

  // CSR
  int eblocks = (EE + 255) / 256;
  hist_dst<<<eblocks, 256, 0, stream>>>(dst, deg);
  scan_offsets<<<1, 1024, 0, stream>>>(deg, offs);
  fill_edges<<<eblocks, 256, 0, stream>>>(src, dst, offs, fptr, ssrc);

  // weights -> merged transposed bf16 (Ws gets +I fold)
  dim3 tb(32, 8), tg(DD / 32, DD / 32, 10);
  transpose_w_all<<<tg, tb, 0, stream>>>(wp, wt);

  // graph boundaries (sorted batch, no atomics)
  graph_bounds<<<(NN + 255) / 256, 256, 0, stream>>>(batch, gstart);

  // fused cooperative persistent kernel: convert + 5 layers
  {
    const float* a0 = x_in;
    unsigned short* a1 = m0;
    unsigned short* a2 = m1;
    const unsigned short* a3 = wt;
    const int* a4 = offs;
    const int* a5 = ssrc;
    void* kargs[] = {(void*)&a0, (void*)&a1, (void*)&a2, (void*)&a3,
                     (void*)&a4, (void*)&a5, (void*)&bp};
    hipError_t err = hipLaunchCooperativeKernel((void*)fused_layers,
                                                dim3(NBLK), dim3(256),
                                                kargs, 0, stream);
    if (err != hipSuccess) {
      // fallback: serial per-phase dispatches (same math)
      convert_x<<<(NN * DD / 2 + 255) / 256, 256, 0, stream>>>(x_in, m0);
      unsigned short* mc = m0;
      unsigned short* mn = m1;
      for (int l = 0; l < 5; ++l) {
        seg_sum<<<(NN + 3) / 4, 256, 0, stream>>>(mc, offs, ssrc);
        gemm_full<<<NBLK, 256, 0, stream>>>(mc, wt + (size_t)l * DD * 1024,
                                            bp.p[l], mn, l < 4 ? 1 : 0);
        unsigned short* t = mc; mc = mn; mn = t;
      }
    }
  }

  // pooling + final linear (final x is in m1 after 5 layers)
  dim3 pgrid(GG, 8);
  pool_partial<<<pgrid, 256, 0, stream>>>(m1, gstart, pooled);
  dim3 fgrid(GG, 4);
  final_linear<<<fgrid, 128, 0, stream>>>(pooled, gstart, Wlin, blin, out);
}

// Round 6
// 273.122 us; speedup vs baseline: 6.3207x; 6.3207x over previous
//
#include <hip/hip_runtime.h>
#include <hip/hip_bf16.h>

#define NN 10000
#define EE 160000
#define DD 512
#define GG 64
#define OUTC 128
#define NBLK 628

typedef __attribute__((ext_vector_type(8))) short bf16x8;
typedef __attribute__((ext_vector_type(4))) float f32x4;

static __device__ __forceinline__ unsigned short f2bf(float f) {
  unsigned u = __builtin_bit_cast(unsigned, f);
  unsigned rounding = 0x7fffu + ((u >> 16) & 1u);
  u += rounding;
  return (unsigned short)(u >> 16);
}

static __device__ __forceinline__ void gload_lds16(const void* g, void* l) {
  __builtin_amdgcn_global_load_lds(
      (const __attribute__((address_space(1))) unsigned*)g,
      (__attribute__((address_space(3))) unsigned*)l, 16, 0, 0);
}

// ---------------- CSR build ----------------
__global__ void hist_dst(const int* __restrict__ dst, int* __restrict__ cnt) {
  int e = blockIdx.x * 256 + threadIdx.x;
  if (e < EE) atomicAdd(&cnt[dst[e]], 1);
}

__global__ void scan_offsets(const int* __restrict__ cnt, int* __restrict__ offs) {
  __shared__ int wpre[17];
  __shared__ int carry;
  int t = threadIdx.x;            // 1024 threads = 16 waves
  int lane = t & 63, wv = t >> 6;
  if (t == 0) carry = 0;
  __syncthreads();
  for (int base = 0; base < NN; base += 1024) {
    int i = base + t;
    int v = (i < NN) ? cnt[i] : 0;
    int s = v;
#pragma unroll
    for (int d = 1; d < 64; d <<= 1) {
      int o = __shfl_up(s, d, 64);
      if (lane >= d) s += o;
    }
    if (lane == 63) wpre[wv] = s;
    __syncthreads();
    if (t == 0) {
      int r = 0;
      for (int w = 0; w < 16; ++w) { int x = wpre[w]; wpre[w] = r; r += x; }
      wpre[16] = r;
    }
    __syncthreads();
    int incl = s + wpre[wv] + carry;
    if (i < NN) offs[i] = incl - v;   // exclusive prefix
    __syncthreads();
    if (t == 0) carry += wpre[16];
    __syncthreads();
  }
  if (t == 0) offs[NN] = carry;       // == EE
}

__global__ void fill_edges(const int* __restrict__ src, const int* __restrict__ dst,
                           const int* __restrict__ offs, int* __restrict__ fptr,
                           int* __restrict__ ssrc) {
  int e = blockIdx.x * 256 + threadIdx.x;
  if (e < EE) {
    int d = dst[e];
    int p = atomicAdd(&fptr[d], 1);
    ssrc[offs[d] + p] = src[e];
  }
}

// ---------------- weight transpose + bf16 convert ----------------
// W [512 k][512 n] f32 row-major -> WT merged [layer][512 n][1024 k] bf16
// Wr at k 0..511; Ws+I at k 512..1023 (residual folded: x + x@Ws = x@(Ws+I))
struct WPtrs { const float* p[10]; };

__global__ void transpose_w_all(WPtrs wp, unsigned short* __restrict__ WT) {
  __shared__ float tile[32][33];
  int z = blockIdx.z;                 // 0..9: layer z>>1, (z&1)=Ws
  const float* W = wp.p[z];
  unsigned short* dst = WT + (size_t)(z >> 1) * DD * 1024 + (size_t)(z & 1) * DD;
  int bx = blockIdx.x * 32, by = blockIdx.y * 32;
  int tx = threadIdx.x, ty = threadIdx.y;
  for (int i = ty; i < 32; i += 8)
    tile[i][tx] = W[(size_t)(by + i) * DD + bx + tx];
  __syncthreads();
  int addI = z & 1;
  for (int i = ty; i < 32; i += 8) {
    float v = tile[tx][i];
    if (addI && (by + tx) == (bx + i)) v += 1.0f;   // fold residual
    dst[(size_t)(bx + i) * 1024 + by + tx] = f2bf(v);
  }
}

// ---------------- x convert: bf16 into merged0 right half ------
__global__ void convert_x(const float* __restrict__ x, unsigned short* __restrict__ m0) {
  int i = blockIdx.x * 256 + threadIdx.x;   // pair index
  if (i < NN * DD / 2) {
    float2 v = ((const float2*)x)[i];
    unsigned u = (unsigned)f2bf(v.x) | ((unsigned)f2bf(v.y) << 16);
    int e = i << 1;
    int row = e >> 9, col = e & 511;
    ((unsigned*)m0)[row * 512 + 256 + (col >> 1)] = u;
  }
}

// ---------------- segment sum: wave per node, 16B lanes, 8-edge ILP ----------
// merged layout per row: [agg(512) | x(512)] bf16.  Reads right half of
// gathered rows, writes left half of own row.
static __device__ __forceinline__ void acc8(float* a, uint4 v) {
  unsigned w0 = v.x, w1 = v.y, w2 = v.z, w3 = v.w;
  a[0] += __builtin_bit_cast(float, w0 << 16);
  a[1] += __builtin_bit_cast(float, w0 & 0xffff0000u);
  a[2] += __builtin_bit_cast(float, w1 << 16);
  a[3] += __builtin_bit_cast(float, w1 & 0xffff0000u);
  a[4] += __builtin_bit_cast(float, w2 << 16);
  a[5] += __builtin_bit_cast(float, w2 & 0xffff0000u);
  a[6] += __builtin_bit_cast(float, w3 << 16);
  a[7] += __builtin_bit_cast(float, w3 & 0xffff0000u);
}

__global__ __launch_bounds__(256) void seg_sum(unsigned short* __restrict__ merged,
                                               const int* __restrict__ offs,
                                               const int* __restrict__ ssrc) {
  int node = (blockIdx.x << 2) + (threadIdx.x >> 6);
  if (node >= NN) return;
  int lane = threadIdx.x & 63;
  int beg = offs[node], end = offs[node + 1];
  const uint4* xb = (const uint4*)merged;   // row = 128 uint4; right half at +64
  float a[8] = {0.f, 0.f, 0.f, 0.f, 0.f, 0.f, 0.f, 0.f};
  int e = beg;
  for (; e + 8 <= end; e += 8) {
    uint4 v0 = xb[(size_t)ssrc[e] * 128 + 64 + lane];
    uint4 v1 = xb[(size_t)ssrc[e + 1] * 128 + 64 + lane];
    uint4 v2 = xb[(size_t)ssrc[e + 2] * 128 + 64 + lane];
    uint4 v3 = xb[(size_t)ssrc[e + 3] * 128 + 64 + lane];
    uint4 v4 = xb[(size_t)ssrc[e + 4] * 128 + 64 + lane];
    uint4 v5 = xb[(size_t)ssrc[e + 5] * 128 + 64 + lane];
    uint4 v6 = xb[(size_t)ssrc[e + 6] * 128 + 64 + lane];
    uint4 v7 = xb[(size_t)ssrc[e + 7] * 128 + 64 + lane];
    acc8(a, v0); acc8(a, v1); acc8(a, v2); acc8(a, v3);
    acc8(a, v4); acc8(a, v5); acc8(a, v6); acc8(a, v7);
  }
  for (; e + 4 <= end; e += 4) {
    uint4 v0 = xb[(size_t)ssrc[e] * 128 + 64 + lane];
    uint4 v1 = xb[(size_t)ssrc[e + 1] * 128 + 64 + lane];
    uint4 v2 = xb[(size_t)ssrc[e + 2] * 128 + 64 + lane];
    uint4 v3 = xb[(size_t)ssrc[e + 3] * 128 + 64 + lane];
    acc8(a, v0); acc8(a, v1); acc8(a, v2); acc8(a, v3);
  }
  for (; e < end; ++e) {
    uint4 v = xb[(size_t)ssrc[e] * 128 + 64 + lane];
    acc8(a, v);
  }
  uint4 o;
  o.x = (unsigned)f2bf(a[0]) | ((unsigned)f2bf(a[1]) << 16);
  o.y = (unsigned)f2bf(a[2]) | ((unsigned)f2bf(a[3]) << 16);
  o.z = (unsigned)f2bf(a[4]) | ((unsigned)f2bf(a[5]) << 16);
  o.w = (unsigned)f2bf(a[6]) | ((unsigned)f2bf(a[7]) << 16);
  ((uint4*)merged)[(size_t)node * 128 + lane] = o;
}

// ---------------- fused layer GEMM --------------------------------------
// C[row,col] = sum_k merged[row][k] * WT[col][k]  (k 0..1023 = agg@Wr + x@(Ws+I))
// then + bias, ReLU, write bf16 into NEXT merged buffer's right half.
// Residual lives in the folded identity — no residual read in epilogue.
// Tile 64x128, BK=64, 4 waves (each 32x64), dbuf LDS via global_load_lds(16B),
// XOR chunk swizzle on global src AND ds_read (conflict-free, verified r3).
// Grid: 157*4 = 628 blocks, XCD-bijective swizzle (628 = 8*78+4, m204).
__global__ __launch_bounds__(256) void gemm_layer(
    const unsigned short* __restrict__ Am,    // merged cur [NN][1024]
    const unsigned short* __restrict__ Bw,    // [512 n][1024 k]
    const float* __restrict__ bias,
    unsigned short* __restrict__ xout,        // merged next (write right half)
    int do_relu) {
  __shared__ unsigned short Al[2][64 * 64];
  __shared__ unsigned short Bl[2][128 * 64];
  int tid = threadIdx.x;
  int lane = tid & 63, wave = tid >> 6;
  int wr = wave >> 1, wc = wave & 1;        // wave tile 32 rows x 64 cols

  // bijective XCD swizzle: nwg=628, q=78, r=4
  int orig = blockIdx.x;
  int xcd = orig & 7, cidx = orig >> 3;
  int wgid = (xcd < 4) ? xcd * 79 + cidx : 316 + (xcd - 4) * 78 + cidx;
  int brow = (wgid >> 2) * 64;
  int bcol = (wgid & 3) * 128;
  int lrow = lane & 15, lq = lane >> 4;

  f32x4 acc[2][4];
#pragma unroll
  for (int m = 0; m < 2; ++m)
#pragma unroll
    for (int n = 0; n < 4; ++n) acc[m][n] = (f32x4){0.f, 0.f, 0.f, 0.f};

  auto STAGE = [&](int buf, int t) {
    int k0 = t * 64;
#pragma unroll
    for (int i = 0; i < 2; ++i) {           // A: 64 rows x 8 chunks
      int idx = i * 256 + tid;
      int row = idx >> 3, c = idx & 7;
      int csw = (c ^ (row & 7)) * 8;
      int gr = brow + row;
      if (gr >= NN) gr = NN - 1;            // clamp; OOB rows never stored
      gload_lds16(Am + (size_t)gr * 1024 + k0 + csw, &Al[buf][idx * 8]);
    }
#pragma unroll
    for (int i = 0; i < 4; ++i) {           // B: 128 rows x 8 chunks
      int idx = i * 256 + tid;
      int row = idx >> 3, c = idx & 7;
      int csw = (c ^ (row & 7)) * 8;
      gload_lds16(Bw + (size_t)(bcol + row) * 1024 + k0 + csw, &Bl[buf][idx * 8]);
    }
  };

  STAGE(0, 0);
  __syncthreads();                            // buf0 ready
  int cur = 0;
#pragma unroll 1
  for (int t = 0; t < 16; ++t) {
    if (t < 15) STAGE(cur ^ 1, t + 1);        // in flight under compute
#pragma unroll
    for (int kk = 0; kk < 2; ++kk) {
      bf16x8 a[2], b[4];
      int lc = kk * 4 + lq;                   // logical 16B chunk 0..7
#pragma unroll
      for (int m = 0; m < 2; ++m) {
        int row = wr * 32 + m * 16 + lrow;
        a[m] = *(const bf16x8*)&Al[cur][row * 64 + ((lc ^ (lrow & 7)) * 8)];
      }
#pragma unroll
      for (int n = 0; n < 4; ++n) {
        int row = wc * 64 + n * 16 + lrow;
        b[n] = *(const bf16x8*)&Bl[cur][row * 64 + ((lc ^ (lrow & 7)) * 8)];
      }
#pragma unroll
      for (int m = 0; m < 2; ++m)
#pragma unroll
        for (int n = 0; n < 4; ++n)
          acc[m][n] = __builtin_amdgcn_mfma_f32_16x16x32_bf16(a[m], b[n], acc[m][n], 0, 0, 0);
    }
    __syncthreads();                          // compute done; next buf staged
    cur ^= 1;
  }

  // epilogue: C row=(lane>>4)*4+i, col=lane&15 within each 16x16 fragment
  int crow = lq * 4, ccol = lrow;
#pragma unroll
  for (int m = 0; m < 2; ++m) {
#pragma unroll
    for (int n = 0; n < 4; ++n) {
      int col = bcol + wc * 64 + n * 16 + ccol;
      float bv = bias[col];
#pragma unroll
      for (int i = 0; i < 4; ++i) {
        int row = brow + wr * 32 + m * 16 + crow + i;
        if (row < NN) {
          float v = acc[m][n][i] + bv;
          if (do_relu) v = fmaxf(v, 0.f);
          xout[(size_t)row * 1024 + 512 + col] = f2bf(v);
        }
      }
    }
  }
}

// ---------------- pooling ----------------
// batch is sorted: find graph boundaries with disjoint writes (no atomics).
__global__ void graph_bounds(const int* __restrict__ batch, int* __restrict__ gstart) {
  int i = blockIdx.x * 256 + threadIdx.x;
  if (i >= NN) return;
  int cur = batch[i];
  int prev = (i == 0) ? -1 : batch[i - 1];
  for (int g = prev + 1; g <= cur; ++g) gstart[g] = i;
  if (i == NN - 1)
    for (int g = cur + 1; g <= GG; ++g) gstart[g] = NN;
}

// reads bf16 final x from merged right half
__global__ __launch_bounds__(256) void pool_partial(const unsigned short* __restrict__ mfin,
                                                    const int* __restrict__ gstart,
                                                    float* __restrict__ pooled) {
  int g = blockIdx.x, part = blockIdx.y;    // 8 parts per graph
  int t = threadIdx.x;                      // 256 threads: col pair 2t,2t+1
  int beg = gstart[g], end = gstart[g + 1];
  int n = end - beg;
  int per = (n + 7) >> 3;
  int b = beg + part * per;
  int e = b + per; if (e > end) e = end;
  if (b >= e) return;
  const unsigned* mw = (const unsigned*)mfin;
  float a0 = 0.f, a1 = 0.f;
  for (int r = b; r < e; ++r) {
    unsigned v = mw[(size_t)r * 512 + 256 + t];
    a0 += __builtin_bit_cast(float, v << 16);
    a1 += __builtin_bit_cast(float, v & 0xffff0000u);
  }
  atomicAdd(&pooled[g * DD + 2 * t], a0);
  atomicAdd(&pooled[g * DD + 2 * t + 1], a1);
}

// grid (GG, 4): each block computes 128-k-slice partial of out[g][*]
__global__ __launch_bounds__(128) void final_linear(const float* __restrict__ pooled,
                                                    const int* __restrict__ gstart,
                                                    const float* __restrict__ Wlin,
                                                    const float* __restrict__ blin,
                                                    float* __restrict__ out) {
  __shared__ float p[128];
  int g = blockIdx.x, kq = blockIdx.y;
  int o = threadIdx.x;
  int cnt = gstart[g + 1] - gstart[g];
  float inv = 1.0f / fmaxf((float)cnt, 1.0f);
  p[o] = pooled[g * DD + kq * 128 + o] * inv;
  __syncthreads();
  float s = (kq == 0) ? blin[o] : 0.f;
#pragma unroll 8
  for (int k = 0; k < 128; ++k)
    s += p[k] * Wlin[(size_t)(kq * 128 + k) * OUTC + o];
  atomicAdd(&out[g * OUTC + o], s);
}

// ---------------- host ----------------
extern "C" void kernel_launch(void* const* d_in, const int* in_sizes, int n_in,
                              void* d_out, int out_size, void* d_ws, size_t ws_size,
                              hipStream_t stream) {
  const float* x_in = (const float*)d_in[0];
  const int* ei = (const int*)d_in[1];
  const int* src = ei;
  const int* dst = ei + EE;
  const int* batch = (const int*)d_in[2];
  WPtrs wp;
  const float* bias[5];
  for (int l = 0; l < 5; ++l) {
    wp.p[2 * l] = (const float*)d_in[3 + 3 * l];      // Wr
    wp.p[2 * l + 1] = (const float*)d_in[4 + 3 * l];  // Ws
    bias[l] = (const float*)d_in[5 + 3 * l];
  }
  const float* Wlin = (const float*)d_in[18];
  const float* blin = (const float*)d_in[19];
  float* out = (float*)d_out;

  char* ws = (char*)d_ws;
  size_t off = 0;
  auto alloc = [&](size_t bytes) { size_t o = off; off += (bytes + 511) & ~(size_t)511; return o; };
  unsigned short* m0 = (unsigned short*)(ws + alloc((size_t)NN * 1024 * 2));
  unsigned short* m1 = (unsigned short*)(ws + alloc((size_t)NN * 1024 * 2));
  unsigned short* wt = (unsigned short*)(ws + alloc((size_t)5 * DD * 1024 * 2));
  int* deg = (int*)(ws + alloc((size_t)2 * NN * 4));   // deg | fptr contiguous
  int* fptr = deg + NN;
  int* offs = (int*)(ws + alloc((size_t)(NN + 1) * 4));
  int* ssrc = (int*)(ws + alloc((size_t)EE * 4));
  int* gstart = (int*)(ws + alloc((size_t)(GG + 1) * 4));
  float* pooled = (float*)(ws + alloc((size_t)GG * DD * 4));

  hipMemsetAsync(deg, 0, (size_t)2 * NN * 4, stream);  // deg + fptr
  hipMemsetAsync(pooled, 0, (size_t)GG * DD * 4, stream);
  hipMemsetAsync(out, 0, (size_t)GG * OUTC * 4, stream);

  // CSR
  int eblocks = (EE + 255) / 256;
  hist_dst<<<eblocks, 256, 0, stream>>>(dst, deg);
  scan_offsets<<<1, 1024, 0, stream>>>(deg, offs);
  fill_edges<<<eblocks, 256, 0, stream>>>(src, dst, offs, fptr, ssrc);

  // weights -> merged transposed bf16 (Ws gets +I fold)
  dim3 tb(32, 8), tg(DD / 32, DD / 32, 10);
  transpose_w_all<<<tg, tb, 0, stream>>>(wp, wt);

  // x -> bf16 right half of merged0
  convert_x<<<(NN * DD / 2 + 255) / 256, 256, 0, stream>>>(x_in, m0);

  // graph boundaries (sorted batch, no atomics)
  graph_bounds<<<(NN + 255) / 256, 256, 0, stream>>>(batch, gstart);

  // layers
  unsigned short* mc = m0;
  unsigned short* mn = m1;
  for (int l = 0; l < 5; ++l) {
    seg_sum<<<(NN + 3) / 4, 256, 0, stream>>>(mc, offs, ssrc);
    gemm_layer<<<NBLK, 256, 0, stream>>>(mc, wt + (size_t)l * DD * 1024,
                                         bias[l], mn, l < 4 ? 1 : 0);
    unsigned short* t = mc; mc = mn; mn = t;
  }

  // pooling + final linear (mc == final merged buffer after 5 swaps)
  dim3 pgrid(GG, 8);
  pool_partial<<<pgrid, 256, 0, stream>>>(mc, gstart, pooled);
  dim3 fgrid(GG, 4);
  final_linear<<<fgrid, 128, 0, stream>>>(pooled, gstart, Wlin, blin, out);
}

// Round 7
// 266.791 us; speedup vs baseline: 6.4708x; 1.0237x over previous
//
#include <hip/hip_runtime.h>
#include <hip/hip_bf16.h>

#define NN 10000
#define EE 160000
#define DD 512
#define GG 64
#define OUTC 128
#define NBLK 628

typedef __attribute__((ext_vector_type(8))) short bf16x8;
typedef __attribute__((ext_vector_type(4))) float f32x4;

static __device__ __forceinline__ unsigned short f2bf(float f) {
  unsigned u = __builtin_bit_cast(unsigned, f);
  unsigned rounding = 0x7fffu + ((u >> 16) & 1u);
  u += rounding;
  return (unsigned short)(u >> 16);
}

static __device__ __forceinline__ void gload_lds16(const void* g, void* l) {
  __builtin_amdgcn_global_load_lds(
      (const __attribute__((address_space(1))) unsigned*)g,
      (__attribute__((address_space(3))) unsigned*)l, 16, 0, 0);
}

// ---------------- CSR build ----------------
__global__ void hist_dst(const int* __restrict__ dst, int* __restrict__ cnt) {
  int e = blockIdx.x * 256 + threadIdx.x;
  if (e < EE) atomicAdd(&cnt[dst[e]], 1);
}

__global__ void scan_offsets(const int* __restrict__ cnt, int* __restrict__ offs) {
  __shared__ int wpre[17];
  __shared__ int carry;
  int t = threadIdx.x;            // 1024 threads = 16 waves
  int lane = t & 63, wv = t >> 6;
  if (t == 0) carry = 0;
  __syncthreads();
  for (int base = 0; base < NN; base += 1024) {
    int i = base + t;
    int v = (i < NN) ? cnt[i] : 0;
    int s = v;
#pragma unroll
    for (int d = 1; d < 64; d <<= 1) {
      int o = __shfl_up(s, d, 64);
      if (lane >= d) s += o;
    }
    if (lane == 63) wpre[wv] = s;
    __syncthreads();
    if (t == 0) {
      int r = 0;
      for (int w = 0; w < 16; ++w) { int x = wpre[w]; wpre[w] = r; r += x; }
      wpre[16] = r;
    }
    __syncthreads();
    int incl = s + wpre[wv] + carry;
    if (i < NN) offs[i] = incl - v;   // exclusive prefix
    __syncthreads();
    if (t == 0) carry += wpre[16];
    __syncthreads();
  }
  if (t == 0) offs[NN] = carry;       // == EE
}

__global__ void fill_edges(const int* __restrict__ src, const int* __restrict__ dst,
                           const int* __restrict__ offs, int* __restrict__ fptr,
                           int* __restrict__ ssrc) {
  int e = blockIdx.x * 256 + threadIdx.x;
  if (e < EE) {
    int d = dst[e];
    int p = atomicAdd(&fptr[d], 1);
    ssrc[offs[d] + p] = src[e];
  }
}

// ---------------- weight transpose + bf16 convert ----------------
// W [512 k][512 n] f32 row-major -> WT merged [layer][512 n][1024 k] bf16
// Wr at k 0..511; Ws+I at k 512..1023 (residual folded: x + x@Ws = x@(Ws+I))
struct WPtrs { const float* p[10]; };

__global__ void transpose_w_all(WPtrs wp, unsigned short* __restrict__ WT) {
  __shared__ float tile[32][33];
  int z = blockIdx.z;                 // 0..9: layer z>>1, (z&1)=Ws
  const float* W = wp.p[z];
  unsigned short* dst = WT + (size_t)(z >> 1) * DD * 1024 + (size_t)(z & 1) * DD;
  int bx = blockIdx.x * 32, by = blockIdx.y * 32;
  int tx = threadIdx.x, ty = threadIdx.y;
  for (int i = ty; i < 32; i += 8)
    tile[i][tx] = W[(size_t)(by + i) * DD + bx + tx];
  __syncthreads();
  int addI = z & 1;
  for (int i = ty; i < 32; i += 8) {
    float v = tile[tx][i];
    if (addI && (by + tx) == (bx + i)) v += 1.0f;   // fold residual
    dst[(size_t)(bx + i) * 1024 + by + tx] = f2bf(v);
  }
}

// ---------------- x convert: bf16 into merged0 right half ------
__global__ void convert_x(const float* __restrict__ x, unsigned short* __restrict__ m0) {
  int i = blockIdx.x * 256 + threadIdx.x;   // pair index
  if (i < NN * DD / 2) {
    float2 v = ((const float2*)x)[i];
    unsigned u = (unsigned)f2bf(v.x) | ((unsigned)f2bf(v.y) << 16);
    int e = i << 1;
    int row = e >> 9, col = e & 511;
    ((unsigned*)m0)[row * 512 + 256 + (col >> 1)] = u;
  }
}

// ---------------- segment sum: column-sharded for L2 residency ----------
// merged row = [agg(512) | x(512)] bf16 = 512 uints; x half = uints 256..511.
// 4 col-slices of 128 cols (64 uints).  Grid 10000 blocks: bid&7 = s8,
// slice = s8&3, node-subrange = s8>>2.  Empirical bid%8 -> XCD round-robin
// puts slice s on XCDs {s, s+4}; per-XCD x working set = 2.5 MB -> L2-fits.
// Each (node, slice) computed exactly once: 1250 g x 2 sub x 4 waves = 10000.
__global__ __launch_bounds__(256) void seg_sum_sliced(unsigned short* __restrict__ merged,
                                                      const int* __restrict__ offs,
                                                      const int* __restrict__ ssrc) {
  int bid = blockIdx.x;
  int s8 = bid & 7;
  int g = bid >> 3;                         // 0..1249
  int slice = s8 & 3, sub = s8 >> 2;
  int wave = threadIdx.x >> 6, lane = threadIdx.x & 63;
  int node = (sub * 1250 + g) * 4 + wave;   // 0..9999
  int beg = offs[node], end = offs[node + 1];
  const unsigned* xw = (const unsigned*)merged;
  int co = 256 + slice * 64 + lane;         // uint offset within row
  float a0 = 0.f, a1 = 0.f;
  int e = beg;
#define SEG_LD(i) unsigned v##i = xw[(size_t)ssrc[e + i] * 512 + co]
#define SEG_AC(i)                                          \
  a0 += __builtin_bit_cast(float, v##i << 16);             \
  a1 += __builtin_bit_cast(float, v##i & 0xffff0000u)
  for (; e + 8 <= end; e += 8) {
    SEG_LD(0); SEG_LD(1); SEG_LD(2); SEG_LD(3);
    SEG_LD(4); SEG_LD(5); SEG_LD(6); SEG_LD(7);
    SEG_AC(0); SEG_AC(1); SEG_AC(2); SEG_AC(3);
    SEG_AC(4); SEG_AC(5); SEG_AC(6); SEG_AC(7);
  }
  for (; e + 4 <= end; e += 4) {
    SEG_LD(0); SEG_LD(1); SEG_LD(2); SEG_LD(3);
    SEG_AC(0); SEG_AC(1); SEG_AC(2); SEG_AC(3);
  }
  for (; e < end; ++e) {
    unsigned v = xw[(size_t)ssrc[e] * 512 + co];
    a0 += __builtin_bit_cast(float, v << 16);
    a1 += __builtin_bit_cast(float, v & 0xffff0000u);
  }
#undef SEG_LD
#undef SEG_AC
  unsigned o = (unsigned)f2bf(a0) | ((unsigned)f2bf(a1) << 16);
  ((unsigned*)merged)[(size_t)node * 512 + slice * 64 + lane] = o;
}

// ---------------- fused layer GEMM --------------------------------------
// C[row,col] = sum_k merged[row][k] * WT[col][k]  (k 0..1023 = agg@Wr + x@(Ws+I))
// then + bias, ReLU, write bf16 into NEXT merged buffer's right half.
// Tile 64x128, BK=64, 4 waves (each 32x64), dbuf LDS via global_load_lds(16B),
// XOR chunk swizzle on global src AND ds_read (conflict-free, verified r3).
// Grid: 157*4 = 628 blocks, XCD-bijective swizzle (628 = 8*78+4, m204).
__global__ __launch_bounds__(256) void gemm_layer(
    const unsigned short* __restrict__ Am,    // merged cur [NN][1024]
    const unsigned short* __restrict__ Bw,    // [512 n][1024 k]
    const float* __restrict__ bias,
    unsigned short* __restrict__ xout,        // merged next (write right half)
    int do_relu) {
  __shared__ unsigned short Al[2][64 * 64];
  __shared__ unsigned short Bl[2][128 * 64];
  int tid = threadIdx.x;
  int lane = tid & 63, wave = tid >> 6;
  int wr = wave >> 1, wc = wave & 1;        // wave tile 32 rows x 64 cols

  // bijective XCD swizzle: nwg=628, q=78, r=4
  int orig = blockIdx.x;
  int xcd = orig & 7, cidx = orig >> 3;
  int wgid = (xcd < 4) ? xcd * 79 + cidx : 316 + (xcd - 4) * 78 + cidx;
  int brow = (wgid >> 2) * 64;
  int bcol = (wgid & 3) * 128;
  int lrow = lane & 15, lq = lane >> 4;

  f32x4 acc[2][4];
#pragma unroll
  for (int m = 0; m < 2; ++m)
#pragma unroll
    for (int n = 0; n < 4; ++n) acc[m][n] = (f32x4){0.f, 0.f, 0.f, 0.f};

  auto STAGE = [&](int buf, int t) {
    int k0 = t * 64;
#pragma unroll
    for (int i = 0; i < 2; ++i) {           // A: 64 rows x 8 chunks
      int idx = i * 256 + tid;
      int row = idx >> 3, c = idx & 7;
      int csw = (c ^ (row & 7)) * 8;
      int gr = brow + row;
      if (gr >= NN) gr = NN - 1;            // clamp; OOB rows never stored
      gload_lds16(Am + (size_t)gr * 1024 + k0 + csw, &Al[buf][idx * 8]);
    }
#pragma unroll
    for (int i = 0; i < 4; ++i) {           // B: 128 rows x 8 chunks
      int idx = i * 256 + tid;
      int row = idx >> 3, c = idx & 7;
      int csw = (c ^ (row & 7)) * 8;
      gload_lds16(Bw + (size_t)(bcol + row) * 1024 + k0 + csw, &Bl[buf][idx * 8]);
    }
  };

  STAGE(0, 0);
  __syncthreads();                            // buf0 ready
  int cur = 0;
#pragma unroll 1
  for (int t = 0; t < 16; ++t) {
    if (t < 15) STAGE(cur ^ 1, t + 1);        // in flight under compute
#pragma unroll
    for (int kk = 0; kk < 2; ++kk) {
      bf16x8 a[2], b[4];
      int lc = kk * 4 + lq;                   // logical 16B chunk 0..7
#pragma unroll
      for (int m = 0; m < 2; ++m) {
        int row = wr * 32 + m * 16 + lrow;
        a[m] = *(const bf16x8*)&Al[cur][row * 64 + ((lc ^ (lrow & 7)) * 8)];
      }
#pragma unroll
      for (int n = 0; n < 4; ++n) {
        int row = wc * 64 + n * 16 + lrow;
        b[n] = *(const bf16x8*)&Bl[cur][row * 64 + ((lc ^ (lrow & 7)) * 8)];
      }
#pragma unroll
      for (int m = 0; m < 2; ++m)
#pragma unroll
        for (int n = 0; n < 4; ++n)
          acc[m][n] = __builtin_amdgcn_mfma_f32_16x16x32_bf16(a[m], b[n], acc[m][n], 0, 0, 0);
    }
    __syncthreads();                          // compute done; next buf staged
    cur ^= 1;
  }

  // epilogue: C row=(lane>>4)*4+i, col=lane&15 within each 16x16 fragment
  int crow = lq * 4, ccol = lrow;
#pragma unroll
  for (int m = 0; m < 2; ++m) {
#pragma unroll
    for (int n = 0; n < 4; ++n) {
      int col = bcol + wc * 64 + n * 16 + ccol;
      float bv = bias[col];
#pragma unroll
      for (int i = 0; i < 4; ++i) {
        int row = brow + wr * 32 + m * 16 + crow + i;
        if (row < NN) {
          float v = acc[m][n][i] + bv;
          if (do_relu) v = fmaxf(v, 0.f);
          xout[(size_t)row * 1024 + 512 + col] = f2bf(v);
        }
      }
    }
  }
}

// ---------------- pooling ----------------
// batch is sorted: find graph boundaries with disjoint writes (no atomics).
__global__ void graph_bounds(const int* __restrict__ batch, int* __restrict__ gstart) {
  int i = blockIdx.x * 256 + threadIdx.x;
  if (i >= NN) return;
  int cur = batch[i];
  int prev = (i == 0) ? -1 : batch[i - 1];
  for (int g = prev + 1; g <= cur; ++g) gstart[g] = i;
  if (i == NN - 1)
    for (int g = cur + 1; g <= GG; ++g) gstart[g] = NN;
}

// reads bf16 final x from merged right half
__global__ __launch_bounds__(256) void pool_partial(const unsigned short* __restrict__ mfin,
                                                    const int* __restrict__ gstart,
                                                    float* __restrict__ pooled) {
  int g = blockIdx.x, part = blockIdx.y;    // 8 parts per graph
  int t = threadIdx.x;                      // 256 threads: col pair 2t,2t+1
  int beg = gstart[g], end = gstart[g + 1];
  int n = end - beg;
  int per = (n + 7) >> 3;
  int b = beg + part * per;
  int e = b + per; if (e > end) e = end;
  if (b >= e) return;
  const unsigned* mw = (const unsigned*)mfin;
  float a0 = 0.f, a1 = 0.f;
  for (int r = b; r < e; ++r) {
    unsigned v = mw[(size_t)r * 512 + 256 + t];
    a0 += __builtin_bit_cast(float, v << 16);
    a1 += __builtin_bit_cast(float, v & 0xffff0000u);
  }
  atomicAdd(&pooled[g * DD + 2 * t], a0);
  atomicAdd(&pooled[g * DD + 2 * t + 1], a1);
}

// grid (GG, 4): each block computes 128-k-slice partial of out[g][*]
__global__ __launch_bounds__(128) void final_linear(const float* __restrict__ pooled,
                                                    const int* __restrict__ gstart,
                                                    const float* __restrict__ Wlin,
                                                    const float* __restrict__ blin,
                                                    float* __restrict__ out) {
  __shared__ float p[128];
  int g = blockIdx.x, kq = blockIdx.y;
  int o = threadIdx.x;
  int cnt = gstart[g + 1] - gstart[g];
  float inv = 1.0f / fmaxf((float)cnt, 1.0f);
  p[o] = pooled[g * DD + kq * 128 + o] * inv;
  __syncthreads();
  float s = (kq == 0) ? blin[o] : 0.f;
#pragma unroll 8
  for (int k = 0; k < 128; ++k)
    s += p[k] * Wlin[(size_t)(kq * 128 + k) * OUTC + o];
  atomicAdd(&out[g * OUTC + o], s);
}

// ---------------- host ----------------
extern "C" void kernel_launch(void* const* d_in, const int* in_sizes, int n_in,
                              void* d_out, int out_size, void* d_ws, size_t ws_size,
                              hipStream_t stream) {
  const float* x_in = (const float*)d_in[0];
  const int* ei = (const int*)d_in[1];
  const int* src = ei;
  const int* dst = ei + EE;
  const int* batch = (const int*)d_in[2];
  WPtrs wp;
  const float* bias[5];
  for (int l = 0; l < 5; ++l) {
    wp.p[2 * l] = (const float*)d_in[3 + 3 * l];      // Wr
    wp.p[2 * l + 1] = (const float*)d_in[4 + 3 * l];  // Ws
    bias[l] = (const float*)d_in[5 + 3 * l];
  }
  const float* Wlin = (const float*)d_in[18];
  const float* blin = (const float*)d_in[19];
  float* out = (float*)d_out;

  char* ws = (char*)d_ws;
  size_t off = 0;
  auto alloc = [&](size_t bytes) { size_t o = off; off += (bytes + 511) & ~(size_t)511; return o; };
  unsigned short* m0 = (unsigned short*)(ws + alloc((size_t)NN * 1024 * 2));
  unsigned short* m1 = (unsigned short*)(ws + alloc((size_t)NN * 1024 * 2));
  unsigned short* wt = (unsigned short*)(ws + alloc((size_t)5 * DD * 1024 * 2));
  int* deg = (int*)(ws + alloc((size_t)2 * NN * 4));   // deg | fptr contiguous
  int* fptr = deg + NN;
  int* offs = (int*)(ws + alloc((size_t)(NN + 1) * 4));
  int* ssrc = (int*)(ws + alloc((size_t)EE * 4));
  int* gstart = (int*)(ws + alloc((size_t)(GG + 1) * 4));
  float* pooled = (float*)(ws + alloc((size_t)GG * DD * 4));

  hipMemsetAsync(deg, 0, (size_t)2 * NN * 4, stream);  // deg + fptr
  hipMemsetAsync(pooled, 0, (size_t)GG * DD * 4, stream);
  hipMemsetAsync(out, 0, (size_t)GG * OUTC * 4, stream);

  // CSR
  int eblocks = (EE + 255) / 256;
  hist_dst<<<eblocks, 256, 0, stream>>>(dst, deg);
  scan_offsets<<<1, 1024, 0, stream>>>(deg, offs);
  fill_edges<<<eblocks, 256, 0, stream>>>(src, dst, offs, fptr, ssrc);

  // weights -> merged transposed bf16 (Ws gets +I fold)
  dim3 tb(32, 8), tg(DD / 32, DD / 32, 10);
  transpose_w_all<<<tg, tb, 0, stream>>>(wp, wt);

  // x -> bf16 right half of merged0
  convert_x<<<(NN * DD / 2 + 255) / 256, 256, 0, stream>>>(x_in, m0);

  // graph boundaries (sorted batch, no atomics)
  graph_bounds<<<(NN + 255) / 256, 256, 0, stream>>>(batch, gstart);

  // layers
  unsigned short* mc = m0;
  unsigned short* mn = m1;
  for (int l = 0; l < 5; ++l) {
    seg_sum_sliced<<<10000, 256, 0, stream>>>(mc, offs, ssrc);
    gemm_layer<<<NBLK, 256, 0, stream>>>(mc, wt + (size_t)l * DD * 1024,
                                         bias[l], mn, l < 4 ? 1 : 0);
    unsigned short* t = mc; mc = mn; mn = t;
  }

  // pooling + final linear (mc == final merged buffer after 5 swaps)
  dim3 pgrid(GG, 8);
  pool_partial<<<pgrid, 256, 0, stream>>>(mc, gstart, pooled);
  dim3 fgrid(GG, 4);
  final_linear<<<fgrid, 128, 0, stream>>>(pooled, gstart, Wlin, blin, out);
}